// Round 1
// baseline (1493.784 us; speedup 1.0000x reference)
//
#include <hip/hip_runtime.h>

#define STATE 300
#define NCAUSE 40
#define TT 64
#define NP 4

// ---------------------------------------------------------------------------
// Kernel 1: fused X_pred (A @ X_prev) and vid_recon (C @ X) per (b, p) block.
// LDS tile Xs[k][t'] with t' in [0,64]: t'=0 -> x0 column, t'>=1 -> X[..., t'-1].
//   X_prev column t  == Xs[:, t]
//   X      column t  == Xs[:, t+1]
// 256 threads = 64 t-lanes x 4 row-groups. Weight rows read as float4 from
// global (wave-uniform address -> one L1 transaction broadcast).
// ---------------------------------------------------------------------------
__global__ __launch_bounds__(256, 2)
void pred_recon_kernel(const float* __restrict__ X,
                       const float* __restrict__ x0,
                       const float* __restrict__ A,
                       const float* __restrict__ C,
                       float* __restrict__ vid,     // (B,1,32,32,T)
                       float* __restrict__ Xpred) { // (B,4,300,1,T)
    __shared__ float Xs[STATE * 65];   // 78000 B -> 2 blocks/CU
    const int bp  = blockIdx.x;        // b*4 + p
    const int tid = threadIdx.x;

    const float* __restrict__ Xbp  = X  + (size_t)bp * (STATE * TT);
    const float* __restrict__ x0bp = x0 + (size_t)bp * STATE;

    // Stage shifted tile: Xs[k*65 + tp]
    for (int idx = tid; idx < STATE * 65; idx += 256) {
        const int k  = idx / 65;
        const int tp = idx - k * 65;
        Xs[idx] = (tp == 0) ? x0bp[k] : Xbp[k * TT + (tp - 1)];
    }
    __syncthreads();

    const int t  = tid & 63;
    const int rg = tid >> 6;

    // ---------------- X_pred = A @ X_prev : rows rg*75 .. rg*75+74 ----------
    float* __restrict__ outp = Xpred + (size_t)bp * (STATE * TT);
    for (int chunk = 0; chunk < 15; ++chunk) {
        const int i0 = rg * 75 + chunk * 5;
        float acc[5] = {0.f, 0.f, 0.f, 0.f, 0.f};
        const float4* ar[5];
        #pragma unroll
        for (int r = 0; r < 5; ++r)
            ar[r] = (const float4*)(A + (size_t)(i0 + r) * STATE);

        #pragma unroll 5
        for (int k4 = 0; k4 < STATE / 4; ++k4) {
            const int kb = k4 * 4;
            const float xv0 = Xs[(kb + 0) * 65 + t];
            const float xv1 = Xs[(kb + 1) * 65 + t];
            const float xv2 = Xs[(kb + 2) * 65 + t];
            const float xv3 = Xs[(kb + 3) * 65 + t];
            #pragma unroll
            for (int r = 0; r < 5; ++r) {
                const float4 a = ar[r][k4];
                acc[r] += a.x * xv0 + a.y * xv1 + a.z * xv2 + a.w * xv3;
            }
        }
        #pragma unroll
        for (int r = 0; r < 5; ++r)
            outp[(i0 + r) * TT + t] = acc[r];
    }

    // ---------------- recon = C @ X -> vid (patch_to_image) -----------------
    const int b  = bp >> 2;
    const int p  = bp & 3;
    const int gr = p >> 1;
    const int gc = p & 1;
    // vid[b][0][gr*16+pr][gc*16+pc][t]
    float* __restrict__ vb = vid + (size_t)b * (32 * 32 * TT)
                                 + (size_t)(gr * 16) * (32 * TT)
                                 + (size_t)(gc * 16) * TT;
    for (int chunk = 0; chunk < 16; ++chunk) {
        const int i0 = rg * 64 + chunk * 4;
        float acc[4] = {0.f, 0.f, 0.f, 0.f};
        const float4* cr[4];
        #pragma unroll
        for (int r = 0; r < 4; ++r)
            cr[r] = (const float4*)(C + (size_t)(i0 + r) * STATE);

        #pragma unroll 5
        for (int k4 = 0; k4 < STATE / 4; ++k4) {
            const int kb = k4 * 4;
            const float xv0 = Xs[(kb + 0) * 65 + (t + 1)];
            const float xv1 = Xs[(kb + 1) * 65 + (t + 1)];
            const float xv2 = Xs[(kb + 2) * 65 + (t + 1)];
            const float xv3 = Xs[(kb + 3) * 65 + (t + 1)];
            #pragma unroll
            for (int r = 0; r < 4; ++r) {
                const float4 c = cr[r][k4];
                acc[r] += c.x * xv0 + c.y * xv1 + c.z * xv2 + c.w * xv3;
            }
        }
        #pragma unroll
        for (int r = 0; r < 4; ++r) {
            const int i  = i0 + r;
            const int pr = i >> 4;
            const int pc = i & 15;
            vb[pr * (32 * TT) + pc * TT + t] = acc[r];
        }
    }
}

// ---------------------------------------------------------------------------
// Kernel 2: X_U = 0.1*(1+exp(-Bm@U)) * sum_p |X|   per b block.
// ---------------------------------------------------------------------------
__global__ __launch_bounds__(256, 4)
void xu_kernel(const float* __restrict__ X,
               const float* __restrict__ U,
               const float* __restrict__ Bm,
               float* __restrict__ XU) {  // (B,1,300,1,T)
    __shared__ float Us[NCAUSE * TT];    // 10240 B
    const int b   = blockIdx.x;
    const int tid = threadIdx.x;

    for (int idx = tid; idx < NCAUSE * TT; idx += 256)
        Us[idx] = U[(size_t)b * (NCAUSE * TT) + idx];
    __syncthreads();

    const int t  = tid & 63;
    const int rg = tid >> 6;
    const float* __restrict__ Xb  = X  + (size_t)b * (NP * STATE * TT);
    float* __restrict__ XUb = XU + (size_t)b * (STATE * TT);

    for (int chunk = 0; chunk < 15; ++chunk) {
        const int i0 = rg * 75 + chunk * 5;
        float bu[5] = {0.f, 0.f, 0.f, 0.f, 0.f};
        const float4* mr[5];
        #pragma unroll
        for (int r = 0; r < 5; ++r)
            mr[r] = (const float4*)(Bm + (size_t)(i0 + r) * NCAUSE);

        #pragma unroll
        for (int c4 = 0; c4 < NCAUSE / 4; ++c4) {
            const int cb = c4 * 4;
            const float u0 = Us[(cb + 0) * TT + t];
            const float u1 = Us[(cb + 1) * TT + t];
            const float u2 = Us[(cb + 2) * TT + t];
            const float u3 = Us[(cb + 3) * TT + t];
            #pragma unroll
            for (int r = 0; r < 5; ++r) {
                const float4 m = mr[r][c4];
                bu[r] += m.x * u0 + m.y * u1 + m.z * u2 + m.w * u3;
            }
        }
        #pragma unroll
        for (int r = 0; r < 5; ++r) {
            const int s = i0 + r;
            float sab = 0.f;
            #pragma unroll
            for (int p = 0; p < NP; ++p)
                sab += fabsf(Xb[((size_t)p * STATE + s) * TT + t]);
            const float g = 0.1f * (1.f + __expf(-bu[r]));
            XUb[s * TT + t] = g * sab;
        }
    }
}

extern "C" void kernel_launch(void* const* d_in, const int* in_sizes, int n_in,
                              void* d_out, int out_size, void* d_ws, size_t ws_size,
                              hipStream_t stream) {
    const float* X  = (const float*)d_in[0];   // (256,4,300,1,64)
    const float* U  = (const float*)d_in[1];   // (256,1,40,1,64)
    const float* x0 = (const float*)d_in[2];   // (256,4,300,1)
    const float* A  = (const float*)d_in[3];   // (300,300)
    const float* Bm = (const float*)d_in[4];   // (300,40)
    const float* C  = (const float*)d_in[5];   // (256,300)

    float* out   = (float*)d_out;
    float* vid   = out;                         // 256*32*32*64  = 16777216
    float* Xpred = out + 16777216;              // 256*4*300*64  = 19660800
    float* XU    = out + 16777216 + 19660800;   // 256*300*64    =  4915200

    hipLaunchKernelGGL(pred_recon_kernel, dim3(256 * NP), dim3(256), 0, stream,
                       X, x0, A, C, vid, Xpred);
    hipLaunchKernelGGL(xu_kernel, dim3(256), dim3(256), 0, stream,
                       X, U, Bm, XU);
}